// Round 4
// baseline (217.228 us; speedup 1.0000x reference)
//
#include <hip/hip_runtime.h>
#include <hip/hip_bf16.h>
#include <cstdint>
#include <cstddef>

#define L_SEQ 2048
#define BATCH 2
#define DM 1024
#define NH 16
#define DK 64
#define QKV_N 3072       // 3*DM
#define HEAD_STRIDE 192  // 3*DK
#define NX (4096 * 1024) // X element count
#define NW (3072 * 1024) // W element count

typedef short short8_t __attribute__((ext_vector_type(8)));
typedef short short4_t __attribute__((ext_vector_type(4)));
typedef float f32x4 __attribute__((ext_vector_type(4)));

#define MFMA32(a, b, c) __builtin_amdgcn_mfma_f32_16x16x32_bf16(a, b, c, 0, 0, 0)
#define MFMA16(a, b, c) __builtin_amdgcn_mfma_f32_16x16x16bf16_1k(a, b, c, 0, 0, 0)
// bare v_exp_f32 (2^x). exp2f() is an OCML libm call -- R10 regression.
#define EXP2(x) __builtin_amdgcn_exp2f(x)

// 2x fp32 -> packed bf16 pair (v_cvt_pk_bf16_f32 on gfx950), RNE.
static __device__ __forceinline__ unsigned pk2(float a, float b) {
  __hip_bfloat162 h = __float22bfloat162_rn(make_float2(a, b));
  union { __hip_bfloat162 h; unsigned u; } v;
  v.h = h;
  return v.u;
}

// async global->LDS, 16B per lane. LDS dest = wave-uniform base + lane*16.
static __device__ __forceinline__ void async_copy16(const unsigned short* g,
                                                    unsigned short* l) {
  __builtin_amdgcn_global_load_lds(
      (const __attribute__((address_space(1))) unsigned int*)g,
      (__attribute__((address_space(3))) unsigned int*)l, 16, 0, 0);
}

// ---------------------------------------------------------------------------
// fp32 -> bf16 cast of X and W into one contiguous bf16 buffer.
// ---------------------------------------------------------------------------
__global__ __launch_bounds__(256) void cast_kernel(
    const float* __restrict__ X, const float* __restrict__ W,
    unsigned short* __restrict__ dst) {
  const int e = (blockIdx.x * 256 + threadIdx.x) * 8;
  const float* src = (e < NX) ? &X[e] : &W[e - NX];
  const float4 v0 = *(const float4*)src;
  const float4 v1 = *(const float4*)(src + 4);
  union { short8_t s8; unsigned u[4]; } o;
  o.u[0] = pk2(v0.x, v0.y);
  o.u[1] = pk2(v0.z, v0.w);
  o.u[2] = pk2(v1.x, v1.y);
  o.u[3] = pk2(v1.z, v1.w);
  *(short8_t*)&dst[e] = o.s8;
}

// ---------------------------------------------------------------------------
// bf16 MFMA QKV GEMM, fused RoPE + q-scale epilogue, bf16 output.
// q-scale = 0.125 * log2(e): attention computes softmax in exp2-space.
// Epilogue uses __sincosf (HW v_sin/v_cos) and packed bf16 cvt.
// NOTE: no setprio here -- m190 measured T5 null/negative on lockstep GEMM.
// ---------------------------------------------------------------------------
__global__ __launch_bounds__(256) void qkv_gemm_bf16(
    const unsigned short* __restrict__ Xb, const unsigned short* __restrict__ Wb,
    unsigned short* __restrict__ qkvb) {
  __shared__ __align__(16) unsigned short As[2][128 * 32];  // [buf][m][k]
  __shared__ __align__(16) unsigned short Bs[2][128 * 32];  // [buf][n][k]
  const int t = threadIdx.x;
  const int w = t >> 6;
  const int lane = t & 63;
  const int L16 = lane & 15;
  const int quad = lane >> 4;
  const int m0 = blockIdx.y * 128;
  const int n0 = blockIdx.x * 128;
  const int wm = w & 1;
  const int wn = w >> 1;

  const int c0 = w * 128 + lane;
  const int c1 = c0 + 64;
  const unsigned short* gA0 = Xb + (size_t)(m0 + (c0 >> 2)) * 1024 + (c0 & 3) * 8;
  const unsigned short* gA1 = Xb + (size_t)(m0 + (c1 >> 2)) * 1024 + (c1 & 3) * 8;
  const unsigned short* gB0 = Wb + (size_t)(n0 + (c0 >> 2)) * 1024 + (c0 & 3) * 8;
  const unsigned short* gB1 = Wb + (size_t)(n0 + (c1 >> 2)) * 1024 + (c1 & 3) * 8;

  f32x4 acc[4][4];
#pragma unroll
  for (int i = 0; i < 4; ++i)
#pragma unroll
    for (int j = 0; j < 4; ++j) acc[i][j] = (f32x4){0.f, 0.f, 0.f, 0.f};

  // prologue: stage tile 0 into buf 0
  async_copy16(gA0, &As[0][w * 1024]);
  async_copy16(gA1, &As[0][w * 1024 + 512]);
  async_copy16(gB0, &Bs[0][w * 1024]);
  async_copy16(gB1, &Bs[0][w * 1024 + 512]);

#define GBODY(K0, BUF)                                                        \
  {                                                                           \
    __syncthreads(); /* drains DMA(K0); prior readers of buf done */          \
    if ((K0) + 32 < 1024) {                                                   \
      async_copy16(gA0 + (K0) + 32, &As[(BUF) ^ 1][w * 1024]);                \
      async_copy16(gA1 + (K0) + 32, &As[(BUF) ^ 1][w * 1024 + 512]);          \
      async_copy16(gB0 + (K0) + 32, &Bs[(BUF) ^ 1][w * 1024]);                \
      async_copy16(gB1 + (K0) + 32, &Bs[(BUF) ^ 1][w * 1024 + 512]);          \
    }                                                                         \
    short8_t af[4], bfr[4];                                                   \
    _Pragma("unroll") for (int mt = 0; mt < 4; ++mt)                          \
        af[mt] = *(const short8_t*)                                           \
            &As[BUF][(wm * 64 + mt * 16 + L16) * 32 + quad * 8];              \
    _Pragma("unroll") for (int nt = 0; nt < 4; ++nt)                          \
        bfr[nt] = *(const short8_t*)                                          \
            &Bs[BUF][(wn * 64 + nt * 16 + L16) * 32 + quad * 8];              \
    _Pragma("unroll") for (int mt = 0; mt < 4; ++mt)                          \
        _Pragma("unroll") for (int nt = 0; nt < 4; ++nt)                      \
            acc[mt][nt] = MFMA32(af[mt], bfr[nt], acc[mt][nt]);               \
  }

  for (int k0 = 0; k0 < 1024; k0 += 64) {
    GBODY(k0, 0)
    GBODY(k0 + 32, 1)
  }

  const int nbase = n0 + wn * 64 + L16;
  const int chunk = (n0 >> 6) + wn;
  const int type = chunk % 3;        // 0=q, 1=k, 2=v
  if (type == 2) {
#pragma unroll
    for (int mt = 0; mt < 4; ++mt) {
      const int mbase = m0 + wm * 64 + mt * 16 + quad * 4;
#pragma unroll
      for (int reg = 0; reg < 4; ++reg) {
        const size_t r = (size_t)(mbase + reg) * QKV_N + nbase;
        const unsigned u0 = pk2(acc[mt][0][reg], acc[mt][1][reg]);
        const unsigned u1 = pk2(acc[mt][2][reg], acc[mt][3][reg]);
        qkvb[r]      = (unsigned short)u0;
        qkvb[r + 16] = (unsigned short)(u0 >> 16);
        qkvb[r + 32] = (unsigned short)u1;
        qkvb[r + 48] = (unsigned short)(u1 >> 16);
      }
    }
  } else {
    // q gets 0.125*log2(e) so attention can use bare v_exp (exp2-space).
    const float qs = (type == 0) ? 0.18033688011112042f : 1.0f;
    const float theta = exp2f(-(float)L16 * 0.8304820237218405f);
#pragma unroll
    for (int mt = 0; mt < 4; ++mt) {
      const int mbase = m0 + wm * 64 + mt * 16 + quad * 4;  // even
      const int lb = mbase >> 1;
      float sv[2], cv[2];
      __sincosf((float)lb * theta, &sv[0], &cv[0]);
      __sincosf((float)(lb + 1) * theta, &sv[1], &cv[1]);
#pragma unroll
      for (int reg = 0; reg < 4; ++reg) {
        const int li = reg >> 1;
        const float v0 = acc[mt][0][reg], v1 = acc[mt][1][reg];
        const float r0 = v0 * cv[li] - v1 * sv[li];
        const float r1 = v1 * cv[li] + v0 * sv[li];
        const size_t r = (size_t)(mbase + reg) * QKV_N + nbase;
        const unsigned u0 = pk2(r0 * qs, r1 * qs);
        const unsigned u1 = pk2(acc[mt][2][reg] * qs, acc[mt][3][reg] * qs);
        qkvb[r]      = (unsigned short)u0;
        qkvb[r + 16] = (unsigned short)(u0 >> 16);
        qkvb[r + 32] = (unsigned short)u1;
        qkvb[r + 48] = (unsigned short)(u1 >> 16);
      }
    }
  }
}

// ---------------------------------------------------------------------------
// bf16 MFMA attention, register-resident P, exp2-space softmax.
// R4: revert to R2 tiling (2 m-tiles/wave, 128 q-rows/block, grid 16x32=512;
//   R3's 64-row tiles doubled staging overhead per unit compute -- regressed).
//   Grid-bound at 2 blocks/CU -> VGPRs up to ~256 are free.
// R4 main change: K read DIRECTLY global->register (qkv is 24MB, L2-resident;
//   m169 precedent: LDS-staging L2-fit data is pure overhead). Removes Ks LDS
//   (34.8->18.4KB), 2 DMA/step, 8 ds_read_b128/wave/step, and K's vmcnt-drain
//   coupling at the barrier. kf register double-buffer = T14 one-step
//   prefetch (loads issued a full iteration before use -> zero exposed lat).
//   Direct fragment addr = K[row][quad*8 + half*32] -- no swizzle needed
//   (XOR swizzle was LDS-bank-only; source-swizzle and read-swizzle cancel).
// V keeps the verified LDS micro-transpose path (transpose still needed).
// T5 setprio(1) around MFMA clusters kept.
// ---------------------------------------------------------------------------
__global__ __launch_bounds__(256) void attn_mfma_kernel(
    const unsigned short* __restrict__ qkvb, float* __restrict__ out) {
  __shared__ __align__(16) unsigned short Vt[2][64][72];  // [buf][d][j] swizzled

  const int t = threadIdx.x;
  const int w = t >> 6;
  const int lane = t & 63;
  const int L16 = lane & 15;
  const int quad = lane >> 4;
  const int l0 = blockIdx.x * 128;
  const int b = blockIdx.y & 1;
  const int h = blockIdx.y >> 1;
  const int hoff = h * HEAD_STRIDE;

  const f32x4 z4 = {0.f, 0.f, 0.f, 0.f};

  // ---- hoisted Q B-fragments for 2 m-tiles ----
  short8_t bq[2][2];
#pragma unroll
  for (int mt = 0; mt < 2; ++mt)
#pragma unroll
    for (int kc = 0; kc < 2; ++kc)
      bq[mt][kc] = *(const short8_t*)
          &qkvb[((size_t)((l0 + w * 32 + mt * 16 + L16) * 2 + b)) * QKV_N +
                hoff + kc * 32 + quad * 8];

  f32x4 oc[2][4];
  float l_part[2] = {0.f, 0.f};
#pragma unroll
  for (int mt = 0; mt < 2; ++mt)
#pragma unroll
    for (int dt = 0; dt < 4; ++dt) oc[mt][dt] = z4;

  // ---- K direct-load state: fragment (kt,nt,half) lives at
  //      K[kt*64 + nt*16 + L16][half*32 + quad*8 .. +8)  (cols of head slice)
  const unsigned short* gK =
      qkvb + (size_t)(L16 * 2 + b) * QKV_N + hoff + 64 + quad * 8;

  short8_t kf[2][4][2];  // [buf][nt][half] -- register double-buffer

#define LOAD_K(KT, KB)                                                        \
  _Pragma("unroll") for (int nt = 0; nt < 4; ++nt) {                          \
    const size_t ro = (size_t)(((KT) * 64 + nt * 16) * 2) * QKV_N;            \
    kf[KB][nt][0] = *(const short8_t*)&gK[ro];                                \
    kf[KB][nt][1] = *(const short8_t*)&gK[ro + 32];                           \
  }

  // ---- V prefetch state ----
  const int vr4 = (t >> 4) * 4;
  const int vc4 = (t & 15) * 4;
  const int cgbase = vr4 >> 3;
  const int joff = vr4 & 7;
  short4_t rv[4];

#define LOAD_V(KT)                                                            \
  {                                                                           \
    const int j0 = (KT) * 64;                                                 \
    _Pragma("unroll") for (int r = 0; r < 4; ++r)                             \
        rv[r] = *(const short4_t*)&qkvb[((size_t)((j0 + vr4 + r) * 2 + b)) *  \
                                        QKV_N + hoff + 128 + vc4];            \
  }

  LOAD_V(0)
  LOAD_K(0, 0)

#define ABODY(KT, BUF)                                                        \
  {                                                                           \
    { /* V micro-transpose -> Vt[BUF] */                                      \
      short4_t s0 = {rv[0][0], rv[1][0], rv[2][0], rv[3][0]};                 \
      short4_t s1 = {rv[0][1], rv[1][1], rv[2][1], rv[3][1]};                 \
      short4_t s2 = {rv[0][2], rv[1][2], rv[2][2], rv[3][2]};                 \
      short4_t s3 = {rv[0][3], rv[1][3], rv[2][3], rv[3][3]};                 \
      const int cg0 = (cgbase + ((vc4 >> 2) & 7)) & 7;                        \
      *(short4_t*)&Vt[BUF][vc4 + 0][cg0 * 8 + joff] = s0;                     \
      *(short4_t*)&Vt[BUF][vc4 + 1][cg0 * 8 + joff] = s1;                     \
      *(short4_t*)&Vt[BUF][vc4 + 2][cg0 * 8 + joff] = s2;                     \
      *(short4_t*)&Vt[BUF][vc4 + 3][cg0 * 8 + joff] = s3;                     \
    }                                                                         \
    __syncthreads();                                                          \
    if ((KT) + 1 < 32) {                                                      \
      LOAD_V((KT) + 1)                                                        \
      LOAD_K((KT) + 1, (BUF) ^ 1)                                             \
    }                                                                         \
    f32x4 sc0[4], sc1[4];                                                     \
    __builtin_amdgcn_s_setprio(1);                                            \
    _Pragma("unroll") for (int nt = 0; nt < 4; ++nt) {                        \
      f32x4 t0 = MFMA32(kf[BUF][nt][0], bq[0][0], z4);                        \
      sc0[nt] = MFMA32(kf[BUF][nt][1], bq[0][1], t0);                         \
      f32x4 t1 = MFMA32(kf[BUF][nt][0], bq[1][0], z4);                        \
      sc1[nt] = MFMA32(kf[BUF][nt][1], bq[1][1], t1);                         \
    }                                                                         \
    __builtin_amdgcn_s_setprio(0);                                            \
    short4_t pf[2][4];                                                        \
    _Pragma("unroll") for (int nt = 0; nt < 4; ++nt) {                        \
      float p0 = EXP2(sc0[nt][0]), p1 = EXP2(sc0[nt][1]);                     \
      float p2 = EXP2(sc0[nt][2]), p3 = EXP2(sc0[nt][3]);                     \
      l_part[0] += (p0 + p1) + (p2 + p3);                                     \
      union { short4_t s4; unsigned u[2]; } pu0;                              \
      pu0.u[0] = pk2(p0, p1);                                                 \
      pu0.u[1] = pk2(p2, p3);                                                 \
      pf[0][nt] = pu0.s4;                                                     \
      float q0 = EXP2(sc1[nt][0]), q1 = EXP2(sc1[nt][1]);                     \
      float q2 = EXP2(sc1[nt][2]), q3 = EXP2(sc1[nt][3]);                     \
      l_part[1] += (q0 + q1) + (q2 + q3);                                     \
      union { short4_t s4; unsigned u[2]; } pu1;                              \
      pu1.u[0] = pk2(q0, q1);                                                 \
      pu1.u[1] = pk2(q2, q3);                                                 \
      pf[1][nt] = pu1.s4;                                                     \
    }                                                                         \
    __builtin_amdgcn_s_setprio(1);                                            \
    _Pragma("unroll") for (int nt = 0; nt < 4; ++nt) {                        \
      _Pragma("unroll") for (int dt = 0; dt < 4; ++dt) {                      \
        const int d = dt * 16 + L16;                                          \
        const int g = 2 * nt + (quad >> 1);                                   \
        const int cg = (g + ((d >> 2) & 7)) & 7;                              \
        const short4_t vf =                                                   \
            *(const short4_t*)&Vt[BUF][d][cg * 8 + (quad & 1) * 4];           \
        oc[0][dt] = MFMA16(vf, pf[0][nt], oc[0][dt]);                         \
        oc[1][dt] = MFMA16(vf, pf[1][nt], oc[1][dt]);                         \
      }                                                                       \
    }                                                                         \
    __builtin_amdgcn_s_setprio(0);                                            \
  }

  for (int kt = 0; kt < 32; kt += 2) {
    ABODY(kt, 0)
    ABODY(kt + 1, 1)
  }

  // ---- final row-sum reductions + epilogue ----
#pragma unroll
  for (int mt = 0; mt < 2; ++mt) {
    float l = l_part[mt];
    l += __shfl_xor(l, 16);
    l += __shfl_xor(l, 32);
    const float inv = 1.f / l;
    const int qrow = l0 + w * 32 + mt * 16 + L16;
    const size_t rbase = ((size_t)(qrow * 2 + b)) * DM + h * DK;
#pragma unroll
    for (int dt = 0; dt < 4; ++dt) {
      *(float4*)&out[rbase + dt * 16 + quad * 4] =
          make_float4(oc[mt][dt][0] * inv, oc[mt][dt][1] * inv,
                      oc[mt][dt][2] * inv, oc[mt][dt][3] * inv);
    }
  }
}

// ---------------------------------------------------------------------------
extern "C" void kernel_launch(void* const* d_in, const int* in_sizes, int n_in,
                              void* d_out, int out_size, void* d_ws,
                              size_t ws_size, hipStream_t stream) {
  const float* x = (const float*)d_in[0];
  const float* w = (const float*)d_in[1];
  float* out = (float*)d_out;
  unsigned short* bf = (unsigned short*)d_ws;          // Xb (8MB) + Wb (6MB)
  unsigned short* Xb = bf;
  unsigned short* Wb = bf + NX;
  unsigned short* qkvb =
      (unsigned short*)((char*)d_ws + (16u << 20));    // 24 MB bf16 qkv

  cast_kernel<<<(NX + NW) / (256 * 8), 256, 0, stream>>>(x, w, bf);
  qkv_gemm_bf16<<<dim3(QKV_N / 128, (L_SEQ * BATCH) / 128), 256, 0, stream>>>(
      Xb, Wb, qkvb);
  attn_mfma_kernel<<<dim3(L_SEQ / 128, NH * BATCH), 256, 0, stream>>>(qkvb, out);
}

// Round 5
// 180.552 us; speedup vs baseline: 1.2031x; 1.2031x over previous
//
#include <hip/hip_runtime.h>
#include <hip/hip_bf16.h>
#include <cstdint>
#include <cstddef>

#define L_SEQ 2048
#define BATCH 2
#define DM 1024
#define NH 16
#define DK 64
#define QKV_N 3072       // 3*DM
#define HEAD_STRIDE 192  // 3*DK
#define NX (4096 * 1024) // X element count
#define NW (3072 * 1024) // W element count
#define NROWH (L_SEQ * BATCH * NH)  // 65536 l-sum entries per z

typedef short short8_t __attribute__((ext_vector_type(8)));
typedef short short4_t __attribute__((ext_vector_type(4)));
typedef float f32x4 __attribute__((ext_vector_type(4)));

#define MFMA32(a, b, c) __builtin_amdgcn_mfma_f32_16x16x32_bf16(a, b, c, 0, 0, 0)
#define MFMA16(a, b, c) __builtin_amdgcn_mfma_f32_16x16x16bf16_1k(a, b, c, 0, 0, 0)
// bare v_exp_f32 (2^x). exp2f() is an OCML libm call -- R10 regression.
#define EXP2(x) __builtin_amdgcn_exp2f(x)

// 2x fp32 -> packed bf16 pair (v_cvt_pk_bf16_f32 on gfx950), RNE.
static __device__ __forceinline__ unsigned pk2(float a, float b) {
  __hip_bfloat162 h = __float22bfloat162_rn(make_float2(a, b));
  union { __hip_bfloat162 h; unsigned u; } v;
  v.h = h;
  return v.u;
}

// async global->LDS, 16B per lane. LDS dest = wave-uniform base + lane*16.
static __device__ __forceinline__ void async_copy16(const unsigned short* g,
                                                    unsigned short* l) {
  __builtin_amdgcn_global_load_lds(
      (const __attribute__((address_space(1))) unsigned int*)g,
      (__attribute__((address_space(3))) unsigned int*)l, 16, 0, 0);
}

// ---------------------------------------------------------------------------
// fp32 -> bf16 cast of X and W into one contiguous bf16 buffer.
// ---------------------------------------------------------------------------
__global__ __launch_bounds__(256) void cast_kernel(
    const float* __restrict__ X, const float* __restrict__ W,
    unsigned short* __restrict__ dst) {
  const int e = (blockIdx.x * 256 + threadIdx.x) * 8;
  const float* src = (e < NX) ? &X[e] : &W[e - NX];
  const float4 v0 = *(const float4*)src;
  const float4 v1 = *(const float4*)(src + 4);
  union { short8_t s8; unsigned u[4]; } o;
  o.u[0] = pk2(v0.x, v0.y);
  o.u[1] = pk2(v0.z, v0.w);
  o.u[2] = pk2(v1.x, v1.y);
  o.u[3] = pk2(v1.z, v1.w);
  *(short8_t*)&dst[e] = o.s8;
}

// ---------------------------------------------------------------------------
// bf16 MFMA QKV GEMM, fused RoPE + q-scale epilogue, bf16 output.
// q-scale = 0.125 * log2(e): attention computes softmax in exp2-space.
// NOTE: no setprio here -- m190 measured T5 null/negative on lockstep GEMM.
// ---------------------------------------------------------------------------
__global__ __launch_bounds__(256) void qkv_gemm_bf16(
    const unsigned short* __restrict__ Xb, const unsigned short* __restrict__ Wb,
    unsigned short* __restrict__ qkvb) {
  __shared__ __align__(16) unsigned short As[2][128 * 32];  // [buf][m][k]
  __shared__ __align__(16) unsigned short Bs[2][128 * 32];  // [buf][n][k]
  const int t = threadIdx.x;
  const int w = t >> 6;
  const int lane = t & 63;
  const int L16 = lane & 15;
  const int quad = lane >> 4;
  const int m0 = blockIdx.y * 128;
  const int n0 = blockIdx.x * 128;
  const int wm = w & 1;
  const int wn = w >> 1;

  const int c0 = w * 128 + lane;
  const int c1 = c0 + 64;
  const unsigned short* gA0 = Xb + (size_t)(m0 + (c0 >> 2)) * 1024 + (c0 & 3) * 8;
  const unsigned short* gA1 = Xb + (size_t)(m0 + (c1 >> 2)) * 1024 + (c1 & 3) * 8;
  const unsigned short* gB0 = Wb + (size_t)(n0 + (c0 >> 2)) * 1024 + (c0 & 3) * 8;
  const unsigned short* gB1 = Wb + (size_t)(n0 + (c1 >> 2)) * 1024 + (c1 & 3) * 8;

  f32x4 acc[4][4];
#pragma unroll
  for (int i = 0; i < 4; ++i)
#pragma unroll
    for (int j = 0; j < 4; ++j) acc[i][j] = (f32x4){0.f, 0.f, 0.f, 0.f};

  // prologue: stage tile 0 into buf 0
  async_copy16(gA0, &As[0][w * 1024]);
  async_copy16(gA1, &As[0][w * 1024 + 512]);
  async_copy16(gB0, &Bs[0][w * 1024]);
  async_copy16(gB1, &Bs[0][w * 1024 + 512]);

#define GBODY(K0, BUF)                                                        \
  {                                                                           \
    __syncthreads(); /* drains DMA(K0); prior readers of buf done */          \
    if ((K0) + 32 < 1024) {                                                   \
      async_copy16(gA0 + (K0) + 32, &As[(BUF) ^ 1][w * 1024]);                \
      async_copy16(gA1 + (K0) + 32, &As[(BUF) ^ 1][w * 1024 + 512]);          \
      async_copy16(gB0 + (K0) + 32, &Bs[(BUF) ^ 1][w * 1024]);                \
      async_copy16(gB1 + (K0) + 32, &Bs[(BUF) ^ 1][w * 1024 + 512]);          \
    }                                                                         \
    short8_t af[4], bfr[4];                                                   \
    _Pragma("unroll") for (int mt = 0; mt < 4; ++mt)                          \
        af[mt] = *(const short8_t*)                                           \
            &As[BUF][(wm * 64 + mt * 16 + L16) * 32 + quad * 8];              \
    _Pragma("unroll") for (int nt = 0; nt < 4; ++nt)                          \
        bfr[nt] = *(const short8_t*)                                          \
            &Bs[BUF][(wn * 64 + nt * 16 + L16) * 32 + quad * 8];              \
    _Pragma("unroll") for (int mt = 0; mt < 4; ++mt)                          \
        _Pragma("unroll") for (int nt = 0; nt < 4; ++nt)                      \
            acc[mt][nt] = MFMA32(af[mt], bfr[nt], acc[mt][nt]);               \
  }

  for (int k0 = 0; k0 < 1024; k0 += 64) {
    GBODY(k0, 0)
    GBODY(k0 + 32, 1)
  }

  const int nbase = n0 + wn * 64 + L16;
  const int chunk = (n0 >> 6) + wn;
  const int type = chunk % 3;        // 0=q, 1=k, 2=v
  if (type == 2) {
#pragma unroll
    for (int mt = 0; mt < 4; ++mt) {
      const int mbase = m0 + wm * 64 + mt * 16 + quad * 4;
#pragma unroll
      for (int reg = 0; reg < 4; ++reg) {
        const size_t r = (size_t)(mbase + reg) * QKV_N + nbase;
        const unsigned u0 = pk2(acc[mt][0][reg], acc[mt][1][reg]);
        const unsigned u1 = pk2(acc[mt][2][reg], acc[mt][3][reg]);
        qkvb[r]      = (unsigned short)u0;
        qkvb[r + 16] = (unsigned short)(u0 >> 16);
        qkvb[r + 32] = (unsigned short)u1;
        qkvb[r + 48] = (unsigned short)(u1 >> 16);
      }
    }
  } else {
    // q gets 0.125*log2(e) so attention can use bare v_exp (exp2-space).
    const float qs = (type == 0) ? 0.18033688011112042f : 1.0f;
    const float theta = exp2f(-(float)L16 * 0.8304820237218405f);
#pragma unroll
    for (int mt = 0; mt < 4; ++mt) {
      const int mbase = m0 + wm * 64 + mt * 16 + quad * 4;  // even
      const int lb = mbase >> 1;
      float sv[2], cv[2];
      __sincosf((float)lb * theta, &sv[0], &cv[0]);
      __sincosf((float)(lb + 1) * theta, &sv[1], &cv[1]);
#pragma unroll
      for (int reg = 0; reg < 4; ++reg) {
        const int li = reg >> 1;
        const float v0 = acc[mt][0][reg], v1 = acc[mt][1][reg];
        const float r0 = v0 * cv[li] - v1 * sv[li];
        const float r1 = v1 * cv[li] + v0 * sv[li];
        const size_t r = (size_t)(mbase + reg) * QKV_N + nbase;
        const unsigned u0 = pk2(r0 * qs, r1 * qs);
        const unsigned u1 = pk2(acc[mt][2][reg] * qs, acc[mt][3][reg] * qs);
        qkvb[r]      = (unsigned short)u0;
        qkvb[r + 16] = (unsigned short)(u0 >> 16);
        qkvb[r + 32] = (unsigned short)u1;
        qkvb[r + 48] = (unsigned short)(u1 >> 16);
      }
    }
  }
}

// ---------------------------------------------------------------------------
// bf16 MFMA attention -- R5: exact R2 body (best measured: 73.5us) + KV-split.
//   R4 post-mortem: K direct global->reg = scattered 16-row x 12KB gather,
//   regressed 56%. K stays in LDS via coalesced DMA. R3 post-mortem: smaller
//   q-tiles double staging per compute. KV-split keeps the ABODY (and its
//   staging:compute ratio) IDENTICAL and doubles blocks: grid (16,32,2),
//   1024 blocks = 4/CU = 16 waves/CU (50% cap, was 25%). Theory: R2 counters
//   show 5500 cyc/step vs ~2800 resource demand -> latency-bound, 2x TLP.
// No running max in this softmax => partials merge by plain addition:
//   z=0 writes unnormalized O to out, z=1 to scratch; l-sums to workspace;
//   merge kernel divides by (l0+l1).
// ---------------------------------------------------------------------------
__global__ __launch_bounds__(256) void attn_mfma_kernel(
    const unsigned short* __restrict__ qkvb, float* __restrict__ out,
    float* __restrict__ part1, float* __restrict__ lsum) {
  __shared__ __align__(16) unsigned short Ks[2][4096];    // [buf][r*64 + swz]
  __shared__ __align__(16) unsigned short Vt[2][64][72];  // [buf][d][j] swizzled

  const int t = threadIdx.x;
  const int w = t >> 6;
  const int lane = t & 63;
  const int L16 = lane & 15;
  const int quad = lane >> 4;
  const int l0 = blockIdx.x * 128;
  const int b = blockIdx.y & 1;
  const int h = blockIdx.y >> 1;
  const int z = blockIdx.z;          // KV-split half: kv rows [z*1024, z*1024+1024)
  const int hoff = h * HEAD_STRIDE;

  const f32x4 z4 = {0.f, 0.f, 0.f, 0.f};

  // ---- hoisted Q B-fragments for 2 m-tiles ----
  short8_t bq[2][2];
#pragma unroll
  for (int mt = 0; mt < 2; ++mt)
#pragma unroll
    for (int kc = 0; kc < 2; ++kc)
      bq[mt][kc] = *(const short8_t*)
          &qkvb[((size_t)((l0 + w * 32 + mt * 16 + L16) * 2 + b)) * QKV_N +
                hoff + kc * 32 + quad * 8];

  f32x4 oc[2][4];
  float l_part[2] = {0.f, 0.f};
#pragma unroll
  for (int mt = 0; mt < 2; ++mt)
#pragma unroll
    for (int dt = 0; dt < 4; ++dt) oc[mt][dt] = z4;

  // ---- K async-copy state (XOR-swizzled source column) ----
  const int kr0 = w * 8 + (lane >> 3);
  const int kcs = ((lane & 7) ^ (lane >> 3)) * 8;
  const size_t kstep = (size_t)128 * QKV_N;
  const unsigned short* gK0 =
      qkvb + (size_t)(kr0 * 2 + b) * QKV_N + hoff + 64 + kcs +
      (size_t)z * 16 * kstep;
  const unsigned short* gK1 = gK0 + (size_t)64 * QKV_N;

  // ---- V prefetch state ----
  const int vr4 = (t >> 4) * 4;
  const int vc4 = (t & 15) * 4;
  const int cgbase = vr4 >> 3;
  const int joff = vr4 & 7;
  const int vrow0 = z * 1024;        // KV-split row base for V
  short4_t rv[4];

#define LOAD_V(KT)                                                            \
  {                                                                           \
    const int j0 = (KT) * 64 + vrow0;                                         \
    _Pragma("unroll") for (int r = 0; r < 4; ++r)                             \
        rv[r] = *(const short4_t*)&qkvb[((size_t)((j0 + vr4 + r) * 2 + b)) *  \
                                        QKV_N + hoff + 128 + vc4];            \
  }

  LOAD_V(0)
  async_copy16(gK0, &Ks[0][w * 512]);
  async_copy16(gK1, &Ks[0][w * 512 + 2048]);

  const int rsw = (L16 & 7);

#define ABODY(KT, BUF)                                                        \
  {                                                                           \
    { /* V micro-transpose -> Vt[BUF] */                                      \
      short4_t s0 = {rv[0][0], rv[1][0], rv[2][0], rv[3][0]};                 \
      short4_t s1 = {rv[0][1], rv[1][1], rv[2][1], rv[3][1]};                 \
      short4_t s2 = {rv[0][2], rv[1][2], rv[2][2], rv[3][2]};                 \
      short4_t s3 = {rv[0][3], rv[1][3], rv[2][3], rv[3][3]};                 \
      const int cg0 = (cgbase + ((vc4 >> 2) & 7)) & 7;                        \
      *(short4_t*)&Vt[BUF][vc4 + 0][cg0 * 8 + joff] = s0;                     \
      *(short4_t*)&Vt[BUF][vc4 + 1][cg0 * 8 + joff] = s1;                     \
      *(short4_t*)&Vt[BUF][vc4 + 2][cg0 * 8 + joff] = s2;                     \
      *(short4_t*)&Vt[BUF][vc4 + 3][cg0 * 8 + joff] = s3;                     \
    }                                                                         \
    __syncthreads();                                                          \
    if ((KT) + 1 < 16) {                                                      \
      async_copy16(gK0 + (size_t)((KT) + 1) * kstep, &Ks[(BUF) ^ 1][w * 512]);\
      async_copy16(gK1 + (size_t)((KT) + 1) * kstep,                          \
                   &Ks[(BUF) ^ 1][w * 512 + 2048]);                           \
      LOAD_V((KT) + 1)                                                        \
    }                                                                         \
    f32x4 sc0[4], sc1[4];                                                     \
    __builtin_amdgcn_s_setprio(1);                                            \
    _Pragma("unroll") for (int nt = 0; nt < 4; ++nt) {                        \
      const short8_t ak0 = *(const short8_t*)                                 \
          &Ks[BUF][(nt * 16 + L16) * 64 + (quad ^ rsw) * 8];                  \
      const short8_t ak1 = *(const short8_t*)                                 \
          &Ks[BUF][(nt * 16 + L16) * 64 + ((quad + 4) ^ rsw) * 8];            \
      f32x4 t0 = MFMA32(ak0, bq[0][0], z4);                                   \
      sc0[nt] = MFMA32(ak1, bq[0][1], t0);                                    \
      f32x4 t1 = MFMA32(ak0, bq[1][0], z4);                                   \
      sc1[nt] = MFMA32(ak1, bq[1][1], t1);                                    \
    }                                                                         \
    __builtin_amdgcn_s_setprio(0);                                            \
    short4_t pf[2][4];                                                        \
    _Pragma("unroll") for (int nt = 0; nt < 4; ++nt) {                        \
      float p0 = EXP2(sc0[nt][0]), p1 = EXP2(sc0[nt][1]);                     \
      float p2 = EXP2(sc0[nt][2]), p3 = EXP2(sc0[nt][3]);                     \
      l_part[0] += (p0 + p1) + (p2 + p3);                                     \
      union { short4_t s4; unsigned u[2]; } pu0;                              \
      pu0.u[0] = pk2(p0, p1);                                                 \
      pu0.u[1] = pk2(p2, p3);                                                 \
      pf[0][nt] = pu0.s4;                                                     \
      float q0 = EXP2(sc1[nt][0]), q1 = EXP2(sc1[nt][1]);                     \
      float q2 = EXP2(sc1[nt][2]), q3 = EXP2(sc1[nt][3]);                     \
      l_part[1] += (q0 + q1) + (q2 + q3);                                     \
      union { short4_t s4; unsigned u[2]; } pu1;                              \
      pu1.u[0] = pk2(q0, q1);                                                 \
      pu1.u[1] = pk2(q2, q3);                                                 \
      pf[1][nt] = pu1.s4;                                                     \
    }                                                                         \
    __builtin_amdgcn_s_setprio(1);                                            \
    _Pragma("unroll") for (int nt = 0; nt < 4; ++nt) {                        \
      _Pragma("unroll") for (int dt = 0; dt < 4; ++dt) {                      \
        const int d = dt * 16 + L16;                                          \
        const int g = 2 * nt + (quad >> 1);                                   \
        const int cg = (g + ((d >> 2) & 7)) & 7;                              \
        const short4_t vf =                                                   \
            *(const short4_t*)&Vt[BUF][d][cg * 8 + (quad & 1) * 4];           \
        oc[0][dt] = MFMA16(vf, pf[0][nt], oc[0][dt]);                         \
        oc[1][dt] = MFMA16(vf, pf[1][nt], oc[1][dt]);                         \
      }                                                                       \
    }                                                                         \
    __builtin_amdgcn_s_setprio(0);                                            \
  }

  for (int kt = 0; kt < 16; kt += 2) {
    ABODY(kt, 0)
    ABODY(kt + 1, 1)
  }

  // ---- epilogue: write UNNORMALIZED partial O + per-row l-sum ----
  float* const obase = (z == 0) ? out : part1;
#pragma unroll
  for (int mt = 0; mt < 2; ++mt) {
    float l = l_part[mt];
    l += __shfl_xor(l, 16);
    l += __shfl_xor(l, 32);
    const int qrow = l0 + w * 32 + mt * 16 + L16;
    const int rowh = (qrow * 2 + b) * NH + h;
    if (quad == 0) lsum[z * NROWH + rowh] = l;
    const size_t rbase = ((size_t)(qrow * 2 + b)) * DM + h * DK;
#pragma unroll
    for (int dt = 0; dt < 4; ++dt) {
      *(float4*)&obase[rbase + dt * 16 + quad * 4] =
          make_float4(oc[mt][dt][0], oc[mt][dt][1],
                      oc[mt][dt][2], oc[mt][dt][3]);
    }
  }
}

// ---------------------------------------------------------------------------
// merge: out = (out_part0 + part1) / (l0 + l1). One float4 per thread.
// Element e = row*1024 + h*64 + d  =>  l index = e>>6 = float4_idx>>4.
// ---------------------------------------------------------------------------
__global__ __launch_bounds__(256) void merge_kernel(
    float* __restrict__ out, const float* __restrict__ part1,
    const float* __restrict__ lsum) {
  const int i = blockIdx.x * 256 + threadIdx.x;  // float4 index
  const float4 a = ((const float4*)out)[i];
  const float4 c = ((const float4*)part1)[i];
  const int li = i >> 4;
  const float inv = 1.f / (lsum[li] + lsum[NROWH + li]);
  ((float4*)out)[i] = make_float4((a.x + c.x) * inv, (a.y + c.y) * inv,
                                  (a.z + c.z) * inv, (a.w + c.w) * inv);
}

// ---------------------------------------------------------------------------
extern "C" void kernel_launch(void* const* d_in, const int* in_sizes, int n_in,
                              void* d_out, int out_size, void* d_ws,
                              size_t ws_size, hipStream_t stream) {
  const float* x = (const float*)d_in[0];
  const float* w = (const float*)d_in[1];
  float* out = (float*)d_out;
  unsigned short* bf = (unsigned short*)d_ws;          // Xb (8MB) + Wb (6MB)
  unsigned short* Xb = bf;
  unsigned short* Wb = bf + NX;
  unsigned short* qkvb =
      (unsigned short*)((char*)d_ws + (16u << 20));    // 24 MB bf16 qkv
  // part1 overlays the DEAD Xb/Wb region (free after gemm); lsum after qkvb.
  float* part1 = (float*)d_ws;                          // 16 MB fp32
  float* lsum = (float*)((char*)d_ws + (40u << 20));    // 2*256 KB

  cast_kernel<<<(NX + NW) / (256 * 8), 256, 0, stream>>>(x, w, bf);
  qkv_gemm_bf16<<<dim3(QKV_N / 128, (L_SEQ * BATCH) / 128), 256, 0, stream>>>(
      Xb, Wb, qkvb);
  attn_mfma_kernel<<<dim3(L_SEQ / 128, NH * BATCH, 2), 256, 0, stream>>>(
      qkvb, out, part1, lsum);
  merge_kernel<<<(L_SEQ * BATCH * DM / 4) / 256, 256, 0, stream>>>(out, part1,
                                                                   lsum);
}

// Round 6
// 175.261 us; speedup vs baseline: 1.2395x; 1.0302x over previous
//
#include <hip/hip_runtime.h>
#include <hip/hip_bf16.h>
#include <cstdint>
#include <cstddef>

#define L_SEQ 2048
#define BATCH 2
#define DM 1024
#define NH 16
#define DK 64
#define QKV_N 3072       // 3*DM
#define HEAD_STRIDE 192  // 3*DK
#define NX (4096 * 1024) // X element count
#define NW (3072 * 1024) // W element count
#define NROWH (L_SEQ * BATCH * NH)  // 65536 l-sum entries per z

typedef short short8_t __attribute__((ext_vector_type(8)));
typedef short short4_t __attribute__((ext_vector_type(4)));
typedef float f32x4 __attribute__((ext_vector_type(4)));

#define MFMA32(a, b, c) __builtin_amdgcn_mfma_f32_16x16x32_bf16(a, b, c, 0, 0, 0)
#define MFMA16(a, b, c) __builtin_amdgcn_mfma_f32_16x16x16bf16_1k(a, b, c, 0, 0, 0)
// bare v_exp_f32 (2^x). exp2f() is an OCML libm call -- R10 regression.
#define EXP2(x) __builtin_amdgcn_exp2f(x)

// 2x fp32 -> packed bf16 pair (v_cvt_pk_bf16_f32 on gfx950), RNE.
static __device__ __forceinline__ unsigned pk2(float a, float b) {
  __hip_bfloat162 h = __float22bfloat162_rn(make_float2(a, b));
  union { __hip_bfloat162 h; unsigned u; } v;
  v.h = h;
  return v.u;
}

// async global->LDS, 16B per lane. LDS dest = wave-uniform base + lane*16.
static __device__ __forceinline__ void async_copy16(const unsigned short* g,
                                                    unsigned short* l) {
  __builtin_amdgcn_global_load_lds(
      (const __attribute__((address_space(1))) unsigned int*)g,
      (__attribute__((address_space(3))) unsigned int*)l, 16, 0, 0);
}

// ---------------------------------------------------------------------------
// fp32 -> bf16 cast of X and W into one contiguous bf16 buffer.
// ---------------------------------------------------------------------------
__global__ __launch_bounds__(256) void cast_kernel(
    const float* __restrict__ X, const float* __restrict__ W,
    unsigned short* __restrict__ dst) {
  const int e = (blockIdx.x * 256 + threadIdx.x) * 8;
  const float* src = (e < NX) ? &X[e] : &W[e - NX];
  const float4 v0 = *(const float4*)src;
  const float4 v1 = *(const float4*)(src + 4);
  union { short8_t s8; unsigned u[4]; } o;
  o.u[0] = pk2(v0.x, v0.y);
  o.u[1] = pk2(v0.z, v0.w);
  o.u[2] = pk2(v1.x, v1.y);
  o.u[3] = pk2(v1.z, v1.w);
  *(short8_t*)&dst[e] = o.s8;
}

// ---------------------------------------------------------------------------
// bf16 MFMA QKV GEMM, fused RoPE + q-scale epilogue, bf16 output.
// q-scale = 0.125 * log2(e): attention computes softmax in exp2-space.
// NOTE: no setprio here -- m190 measured T5 null/negative on lockstep GEMM.
// ---------------------------------------------------------------------------
__global__ __launch_bounds__(256) void qkv_gemm_bf16(
    const unsigned short* __restrict__ Xb, const unsigned short* __restrict__ Wb,
    unsigned short* __restrict__ qkvb) {
  __shared__ __align__(16) unsigned short As[2][128 * 32];  // [buf][m][k]
  __shared__ __align__(16) unsigned short Bs[2][128 * 32];  // [buf][n][k]
  const int t = threadIdx.x;
  const int w = t >> 6;
  const int lane = t & 63;
  const int L16 = lane & 15;
  const int quad = lane >> 4;
  const int m0 = blockIdx.y * 128;
  const int n0 = blockIdx.x * 128;
  const int wm = w & 1;
  const int wn = w >> 1;

  const int c0 = w * 128 + lane;
  const int c1 = c0 + 64;
  const unsigned short* gA0 = Xb + (size_t)(m0 + (c0 >> 2)) * 1024 + (c0 & 3) * 8;
  const unsigned short* gA1 = Xb + (size_t)(m0 + (c1 >> 2)) * 1024 + (c1 & 3) * 8;
  const unsigned short* gB0 = Wb + (size_t)(n0 + (c0 >> 2)) * 1024 + (c0 & 3) * 8;
  const unsigned short* gB1 = Wb + (size_t)(n0 + (c1 >> 2)) * 1024 + (c1 & 3) * 8;

  f32x4 acc[4][4];
#pragma unroll
  for (int i = 0; i < 4; ++i)
#pragma unroll
    for (int j = 0; j < 4; ++j) acc[i][j] = (f32x4){0.f, 0.f, 0.f, 0.f};

  // prologue: stage tile 0 into buf 0
  async_copy16(gA0, &As[0][w * 1024]);
  async_copy16(gA1, &As[0][w * 1024 + 512]);
  async_copy16(gB0, &Bs[0][w * 1024]);
  async_copy16(gB1, &Bs[0][w * 1024 + 512]);

#define GBODY(K0, BUF)                                                        \
  {                                                                           \
    __syncthreads(); /* drains DMA(K0); prior readers of buf done */          \
    if ((K0) + 32 < 1024) {                                                   \
      async_copy16(gA0 + (K0) + 32, &As[(BUF) ^ 1][w * 1024]);                \
      async_copy16(gA1 + (K0) + 32, &As[(BUF) ^ 1][w * 1024 + 512]);          \
      async_copy16(gB0 + (K0) + 32, &Bs[(BUF) ^ 1][w * 1024]);                \
      async_copy16(gB1 + (K0) + 32, &Bs[(BUF) ^ 1][w * 1024 + 512]);          \
    }                                                                         \
    short8_t af[4], bfr[4];                                                   \
    _Pragma("unroll") for (int mt = 0; mt < 4; ++mt)                          \
        af[mt] = *(const short8_t*)                                           \
            &As[BUF][(wm * 64 + mt * 16 + L16) * 32 + quad * 8];              \
    _Pragma("unroll") for (int nt = 0; nt < 4; ++nt)                          \
        bfr[nt] = *(const short8_t*)                                          \
            &Bs[BUF][(wn * 64 + nt * 16 + L16) * 32 + quad * 8];              \
    _Pragma("unroll") for (int mt = 0; mt < 4; ++mt)                          \
        _Pragma("unroll") for (int nt = 0; nt < 4; ++nt)                      \
            acc[mt][nt] = MFMA32(af[mt], bfr[nt], acc[mt][nt]);               \
  }

  for (int k0 = 0; k0 < 1024; k0 += 64) {
    GBODY(k0, 0)
    GBODY(k0 + 32, 1)
  }

  const int nbase = n0 + wn * 64 + L16;
  const int chunk = (n0 >> 6) + wn;
  const int type = chunk % 3;        // 0=q, 1=k, 2=v
  if (type == 2) {
#pragma unroll
    for (int mt = 0; mt < 4; ++mt) {
      const int mbase = m0 + wm * 64 + mt * 16 + quad * 4;
#pragma unroll
      for (int reg = 0; reg < 4; ++reg) {
        const size_t r = (size_t)(mbase + reg) * QKV_N + nbase;
        const unsigned u0 = pk2(acc[mt][0][reg], acc[mt][1][reg]);
        const unsigned u1 = pk2(acc[mt][2][reg], acc[mt][3][reg]);
        qkvb[r]      = (unsigned short)u0;
        qkvb[r + 16] = (unsigned short)(u0 >> 16);
        qkvb[r + 32] = (unsigned short)u1;
        qkvb[r + 48] = (unsigned short)(u1 >> 16);
      }
    }
  } else {
    // q gets 0.125*log2(e) so attention can use bare v_exp (exp2-space).
    const float qs = (type == 0) ? 0.18033688011112042f : 1.0f;
    const float theta = exp2f(-(float)L16 * 0.8304820237218405f);
#pragma unroll
    for (int mt = 0; mt < 4; ++mt) {
      const int mbase = m0 + wm * 64 + mt * 16 + quad * 4;  // even
      const int lb = mbase >> 1;
      float sv[2], cv[2];
      __sincosf((float)lb * theta, &sv[0], &cv[0]);
      __sincosf((float)(lb + 1) * theta, &sv[1], &cv[1]);
#pragma unroll
      for (int reg = 0; reg < 4; ++reg) {
        const int li = reg >> 1;
        const float v0 = acc[mt][0][reg], v1 = acc[mt][1][reg];
        const float r0 = v0 * cv[li] - v1 * sv[li];
        const float r1 = v1 * cv[li] + v0 * sv[li];
        const size_t r = (size_t)(mbase + reg) * QKV_N + nbase;
        const unsigned u0 = pk2(r0 * qs, r1 * qs);
        const unsigned u1 = pk2(acc[mt][2][reg] * qs, acc[mt][3][reg] * qs);
        qkvb[r]      = (unsigned short)u0;
        qkvb[r + 16] = (unsigned short)(u0 >> 16);
        qkvb[r + 32] = (unsigned short)u1;
        qkvb[r + 48] = (unsigned short)(u1 >> 16);
      }
    }
  }
}

// ---------------------------------------------------------------------------
// bf16 MFMA attention -- R6: occupancy is REGISTER-capped, not grid-capped.
//   Evidence: Occupancy ~19-23% constant across R2(512 blk)/R3(1024)/R5(1024);
//   R4 (VGPR 136) collapsed to 10.9%. Theory: CSV VGPR excludes AGPRs;
//   total VGPR+AGPR ~232 -> 2 waves/SIMD hard cap (25% ceiling);
//   R4 ~264 -> 1 wave/SIMD (12.5% ceiling). Both match measurements.
// R6 fixes: (1) __launch_bounds__(256,3) forces total alloc <=170 ->
//   3 waves/SIMD; grid 1024 (KV-split) supplies 3 blocks/CU (LDS 104<=160KB).
//   (2) QK^T/softmax/PV merged per-nt: sc liveness 32->8, pf 16->4 regs,
//   peak live ~110 -> budget reachable without spill. exp (trans pipe) now
//   interleaves with MFMA per-nt (separate pipes co-issue, m114).
// KV-split (z in {0,1}) + addition merge retained: grid headroom required.
// ---------------------------------------------------------------------------
__global__ __launch_bounds__(256, 3) void attn_mfma_kernel(
    const unsigned short* __restrict__ qkvb, float* __restrict__ out,
    float* __restrict__ part1, float* __restrict__ lsum) {
  __shared__ __align__(16) unsigned short Ks[2][4096];    // [buf][r*64 + swz]
  __shared__ __align__(16) unsigned short Vt[2][64][72];  // [buf][d][j] swizzled

  const int t = threadIdx.x;
  const int w = t >> 6;
  const int lane = t & 63;
  const int L16 = lane & 15;
  const int quad = lane >> 4;
  const int l0 = blockIdx.x * 128;
  const int b = blockIdx.y & 1;
  const int h = blockIdx.y >> 1;
  const int z = blockIdx.z;          // KV-split half: kv rows [z*1024, z*1024+1024)
  const int hoff = h * HEAD_STRIDE;

  const f32x4 z4 = {0.f, 0.f, 0.f, 0.f};

  // ---- hoisted Q B-fragments for 2 m-tiles ----
  short8_t bq[2][2];
#pragma unroll
  for (int mt = 0; mt < 2; ++mt)
#pragma unroll
    for (int kc = 0; kc < 2; ++kc)
      bq[mt][kc] = *(const short8_t*)
          &qkvb[((size_t)((l0 + w * 32 + mt * 16 + L16) * 2 + b)) * QKV_N +
                hoff + kc * 32 + quad * 8];

  f32x4 oc[2][4];
  float l_part[2] = {0.f, 0.f};
#pragma unroll
  for (int mt = 0; mt < 2; ++mt)
#pragma unroll
    for (int dt = 0; dt < 4; ++dt) oc[mt][dt] = z4;

  // ---- K async-copy state (XOR-swizzled source column) ----
  const int kr0 = w * 8 + (lane >> 3);
  const int kcs = ((lane & 7) ^ (lane >> 3)) * 8;
  const size_t kstep = (size_t)128 * QKV_N;
  const unsigned short* gK0 =
      qkvb + (size_t)(kr0 * 2 + b) * QKV_N + hoff + 64 + kcs +
      (size_t)z * 16 * kstep;
  const unsigned short* gK1 = gK0 + (size_t)64 * QKV_N;

  // ---- V prefetch state ----
  const int vr4 = (t >> 4) * 4;
  const int vc4 = (t & 15) * 4;
  const int cgbase = vr4 >> 3;
  const int joff = vr4 & 7;
  const int vrow0 = z * 1024;        // KV-split row base for V
  short4_t rv[4];

#define LOAD_V(KT)                                                            \
  {                                                                           \
    const int j0 = (KT) * 64 + vrow0;                                         \
    _Pragma("unroll") for (int r = 0; r < 4; ++r)                             \
        rv[r] = *(const short4_t*)&qkvb[((size_t)((j0 + vr4 + r) * 2 + b)) *  \
                                        QKV_N + hoff + 128 + vc4];            \
  }

  LOAD_V(0)
  async_copy16(gK0, &Ks[0][w * 512]);
  async_copy16(gK1, &Ks[0][w * 512 + 2048]);

  const int rsw = (L16 & 7);

#define ABODY(KT, BUF)                                                        \
  {                                                                           \
    { /* V micro-transpose -> Vt[BUF] */                                      \
      short4_t s0 = {rv[0][0], rv[1][0], rv[2][0], rv[3][0]};                 \
      short4_t s1 = {rv[0][1], rv[1][1], rv[2][1], rv[3][1]};                 \
      short4_t s2 = {rv[0][2], rv[1][2], rv[2][2], rv[3][2]};                 \
      short4_t s3 = {rv[0][3], rv[1][3], rv[2][3], rv[3][3]};                 \
      const int cg0 = (cgbase + ((vc4 >> 2) & 7)) & 7;                        \
      *(short4_t*)&Vt[BUF][vc4 + 0][cg0 * 8 + joff] = s0;                     \
      *(short4_t*)&Vt[BUF][vc4 + 1][cg0 * 8 + joff] = s1;                     \
      *(short4_t*)&Vt[BUF][vc4 + 2][cg0 * 8 + joff] = s2;                     \
      *(short4_t*)&Vt[BUF][vc4 + 3][cg0 * 8 + joff] = s3;                     \
    }                                                                         \
    __syncthreads();                                                          \
    if ((KT) + 1 < 16) {                                                      \
      async_copy16(gK0 + (size_t)((KT) + 1) * kstep, &Ks[(BUF) ^ 1][w * 512]);\
      async_copy16(gK1 + (size_t)((KT) + 1) * kstep,                          \
                   &Ks[(BUF) ^ 1][w * 512 + 2048]);                           \
      LOAD_V((KT) + 1)                                                        \
    }                                                                         \
    __builtin_amdgcn_s_setprio(1);                                            \
    _Pragma("unroll") for (int nt = 0; nt < 4; ++nt) {                        \
      const short8_t ak0 = *(const short8_t*)                                 \
          &Ks[BUF][(nt * 16 + L16) * 64 + (quad ^ rsw) * 8];                  \
      const short8_t ak1 = *(const short8_t*)                                 \
          &Ks[BUF][(nt * 16 + L16) * 64 + ((quad + 4) ^ rsw) * 8];            \
      f32x4 t0 = MFMA32(ak0, bq[0][0], z4);                                   \
      const f32x4 s0v = MFMA32(ak1, bq[0][1], t0);                            \
      f32x4 t1 = MFMA32(ak0, bq[1][0], z4);                                   \
      const f32x4 s1v = MFMA32(ak1, bq[1][1], t1);                            \
      float p0 = EXP2(s0v[0]), p1 = EXP2(s0v[1]);                             \
      float p2 = EXP2(s0v[2]), p3 = EXP2(s0v[3]);                             \
      l_part[0] += (p0 + p1) + (p2 + p3);                                     \
      union { short4_t s4; unsigned u[2]; } pu0;                              \
      pu0.u[0] = pk2(p0, p1);                                                 \
      pu0.u[1] = pk2(p2, p3);                                                 \
      float q0 = EXP2(s1v[0]), q1 = EXP2(s1v[1]);                             \
      float q2 = EXP2(s1v[2]), q3 = EXP2(s1v[3]);                             \
      l_part[1] += (q0 + q1) + (q2 + q3);                                     \
      union { short4_t s4; unsigned u[2]; } pu1;                              \
      pu1.u[0] = pk2(q0, q1);                                                 \
      pu1.u[1] = pk2(q2, q3);                                                 \
      _Pragma("unroll") for (int dt = 0; dt < 4; ++dt) {                      \
        const int d = dt * 16 + L16;                                          \
        const int g = 2 * nt + (quad >> 1);                                   \
        const int cg = (g + ((d >> 2) & 7)) & 7;                              \
        const short4_t vf =                                                   \
            *(const short4_t*)&Vt[BUF][d][cg * 8 + (quad & 1) * 4];           \
        oc[0][dt] = MFMA16(vf, pu0.s4, oc[0][dt]);                            \
        oc[1][dt] = MFMA16(vf, pu1.s4, oc[1][dt]);                            \
      }                                                                       \
    }                                                                         \
    __builtin_amdgcn_s_setprio(0);                                            \
  }

  for (int kt = 0; kt < 16; kt += 2) {
    ABODY(kt, 0)
    ABODY(kt + 1, 1)
  }

  // ---- epilogue: write UNNORMALIZED partial O + per-row l-sum ----
  float* const obase = (z == 0) ? out : part1;
#pragma unroll
  for (int mt = 0; mt < 2; ++mt) {
    float l = l_part[mt];
    l += __shfl_xor(l, 16);
    l += __shfl_xor(l, 32);
    const int qrow = l0 + w * 32 + mt * 16 + L16;
    const int rowh = (qrow * 2 + b) * NH + h;
    if (quad == 0) lsum[z * NROWH + rowh] = l;
    const size_t rbase = ((size_t)(qrow * 2 + b)) * DM + h * DK;
#pragma unroll
    for (int dt = 0; dt < 4; ++dt) {
      *(float4*)&obase[rbase + dt * 16 + quad * 4] =
          make_float4(oc[mt][dt][0], oc[mt][dt][1],
                      oc[mt][dt][2], oc[mt][dt][3]);
    }
  }
}

// ---------------------------------------------------------------------------
// merge: out = (out_part0 + part1) / (l0 + l1). One float4 per thread.
// Element e = row*1024 + h*64 + d  =>  l index = e>>6 = float4_idx>>4.
// ---------------------------------------------------------------------------
__global__ __launch_bounds__(256) void merge_kernel(
    float* __restrict__ out, const float* __restrict__ part1,
    const float* __restrict__ lsum) {
  const int i = blockIdx.x * 256 + threadIdx.x;  // float4 index
  const float4 a = ((const float4*)out)[i];
  const float4 c = ((const float4*)part1)[i];
  const int li = i >> 4;
  const float inv = 1.f / (lsum[li] + lsum[NROWH + li]);
  ((float4*)out)[i] = make_float4((a.x + c.x) * inv, (a.y + c.y) * inv,
                                  (a.z + c.z) * inv, (a.w + c.w) * inv);
}

// ---------------------------------------------------------------------------
extern "C" void kernel_launch(void* const* d_in, const int* in_sizes, int n_in,
                              void* d_out, int out_size, void* d_ws,
                              size_t ws_size, hipStream_t stream) {
  const float* x = (const float*)d_in[0];
  const float* w = (const float*)d_in[1];
  float* out = (float*)d_out;
  unsigned short* bf = (unsigned short*)d_ws;          // Xb (8MB) + Wb (6MB)
  unsigned short* Xb = bf;
  unsigned short* Wb = bf + NX;
  unsigned short* qkvb =
      (unsigned short*)((char*)d_ws + (16u << 20));    // 24 MB bf16 qkv
  // part1 overlays the DEAD Xb/Wb region (free after gemm); lsum after qkvb.
  float* part1 = (float*)d_ws;                          // 16 MB fp32
  float* lsum = (float*)((char*)d_ws + (40u << 20));    // 2*256 KB

  cast_kernel<<<(NX + NW) / (256 * 8), 256, 0, stream>>>(x, w, bf);
  qkv_gemm_bf16<<<dim3(QKV_N / 128, (L_SEQ * BATCH) / 128), 256, 0, stream>>>(
      Xb, Wb, qkvb);
  attn_mfma_kernel<<<dim3(L_SEQ / 128, NH * BATCH, 2), 256, 0, stream>>>(
      qkvb, out, part1, lsum);
  merge_kernel<<<(L_SEQ * BATCH * DM / 4) / 256, 256, 0, stream>>>(out, part1,
                                                                   lsum);
}

// Round 7
// 164.431 us; speedup vs baseline: 1.3211x; 1.0659x over previous
//
#include <hip/hip_runtime.h>
#include <hip/hip_bf16.h>
#include <cstdint>
#include <cstddef>

#define L_SEQ 2048
#define BATCH 2
#define DM 1024
#define NH 16
#define DK 64
#define QKV_N 3072       // 3*DM
#define HEAD_STRIDE 192  // 3*DK
#define NX (4096 * 1024) // X element count
#define NW (3072 * 1024) // W element count

typedef short short8_t __attribute__((ext_vector_type(8)));
typedef short short4_t __attribute__((ext_vector_type(4)));
typedef float f32x4 __attribute__((ext_vector_type(4)));

#define MFMA32(a, b, c) __builtin_amdgcn_mfma_f32_16x16x32_bf16(a, b, c, 0, 0, 0)
#define MFMA16(a, b, c) __builtin_amdgcn_mfma_f32_16x16x16bf16_1k(a, b, c, 0, 0, 0)
// bare v_exp_f32 (2^x). exp2f() is an OCML libm call -- R10 regression.
#define EXP2(x) __builtin_amdgcn_exp2f(x)

// 2x fp32 -> packed bf16 pair (v_cvt_pk_bf16_f32 on gfx950), RNE.
static __device__ __forceinline__ unsigned pk2(float a, float b) {
  __hip_bfloat162 h = __float22bfloat162_rn(make_float2(a, b));
  union { __hip_bfloat162 h; unsigned u; } v;
  v.h = h;
  return v.u;
}

// async global->LDS, 16B per lane. LDS dest = wave-uniform base + lane*16.
static __device__ __forceinline__ void async_copy16(const unsigned short* g,
                                                    unsigned short* l) {
  __builtin_amdgcn_global_load_lds(
      (const __attribute__((address_space(1))) unsigned int*)g,
      (__attribute__((address_space(3))) unsigned int*)l, 16, 0, 0);
}

// ---------------------------------------------------------------------------
// fp32 -> bf16 cast of X and W into one contiguous bf16 buffer.
// ---------------------------------------------------------------------------
__global__ __launch_bounds__(256) void cast_kernel(
    const float* __restrict__ X, const float* __restrict__ W,
    unsigned short* __restrict__ dst) {
  const int e = (blockIdx.x * 256 + threadIdx.x) * 8;
  const float* src = (e < NX) ? &X[e] : &W[e - NX];
  const float4 v0 = *(const float4*)src;
  const float4 v1 = *(const float4*)(src + 4);
  union { short8_t s8; unsigned u[4]; } o;
  o.u[0] = pk2(v0.x, v0.y);
  o.u[1] = pk2(v0.z, v0.w);
  o.u[2] = pk2(v1.x, v1.y);
  o.u[3] = pk2(v1.z, v1.w);
  *(short8_t*)&dst[e] = o.s8;
}

// ---------------------------------------------------------------------------
// bf16 MFMA QKV GEMM, fused RoPE + q-scale epilogue, bf16 output.
// q-scale = 0.125 * log2(e): attention computes softmax in exp2-space.
// NOTE: no setprio here -- m190 measured T5 null/negative on lockstep GEMM.
// ---------------------------------------------------------------------------
__global__ __launch_bounds__(256) void qkv_gemm_bf16(
    const unsigned short* __restrict__ Xb, const unsigned short* __restrict__ Wb,
    unsigned short* __restrict__ qkvb) {
  __shared__ __align__(16) unsigned short As[2][128 * 32];  // [buf][m][k]
  __shared__ __align__(16) unsigned short Bs[2][128 * 32];  // [buf][n][k]
  const int t = threadIdx.x;
  const int w = t >> 6;
  const int lane = t & 63;
  const int L16 = lane & 15;
  const int quad = lane >> 4;
  const int m0 = blockIdx.y * 128;
  const int n0 = blockIdx.x * 128;
  const int wm = w & 1;
  const int wn = w >> 1;

  const int c0 = w * 128 + lane;
  const int c1 = c0 + 64;
  const unsigned short* gA0 = Xb + (size_t)(m0 + (c0 >> 2)) * 1024 + (c0 & 3) * 8;
  const unsigned short* gA1 = Xb + (size_t)(m0 + (c1 >> 2)) * 1024 + (c1 & 3) * 8;
  const unsigned short* gB0 = Wb + (size_t)(n0 + (c0 >> 2)) * 1024 + (c0 & 3) * 8;
  const unsigned short* gB1 = Wb + (size_t)(n0 + (c1 >> 2)) * 1024 + (c1 & 3) * 8;

  f32x4 acc[4][4];
#pragma unroll
  for (int i = 0; i < 4; ++i)
#pragma unroll
    for (int j = 0; j < 4; ++j) acc[i][j] = (f32x4){0.f, 0.f, 0.f, 0.f};

  // prologue: stage tile 0 into buf 0
  async_copy16(gA0, &As[0][w * 1024]);
  async_copy16(gA1, &As[0][w * 1024 + 512]);
  async_copy16(gB0, &Bs[0][w * 1024]);
  async_copy16(gB1, &Bs[0][w * 1024 + 512]);

#define GBODY(K0, BUF)                                                        \
  {                                                                           \
    __syncthreads(); /* drains DMA(K0); prior readers of buf done */          \
    if ((K0) + 32 < 1024) {                                                   \
      async_copy16(gA0 + (K0) + 32, &As[(BUF) ^ 1][w * 1024]);                \
      async_copy16(gA1 + (K0) + 32, &As[(BUF) ^ 1][w * 1024 + 512]);          \
      async_copy16(gB0 + (K0) + 32, &Bs[(BUF) ^ 1][w * 1024]);                \
      async_copy16(gB1 + (K0) + 32, &Bs[(BUF) ^ 1][w * 1024 + 512]);          \
    }                                                                         \
    short8_t af[4], bfr[4];                                                   \
    _Pragma("unroll") for (int mt = 0; mt < 4; ++mt)                          \
        af[mt] = *(const short8_t*)                                           \
            &As[BUF][(wm * 64 + mt * 16 + L16) * 32 + quad * 8];              \
    _Pragma("unroll") for (int nt = 0; nt < 4; ++nt)                          \
        bfr[nt] = *(const short8_t*)                                          \
            &Bs[BUF][(wn * 64 + nt * 16 + L16) * 32 + quad * 8];              \
    _Pragma("unroll") for (int mt = 0; mt < 4; ++mt)                          \
        _Pragma("unroll") for (int nt = 0; nt < 4; ++nt)                      \
            acc[mt][nt] = MFMA32(af[mt], bfr[nt], acc[mt][nt]);               \
  }

  for (int k0 = 0; k0 < 1024; k0 += 64) {
    GBODY(k0, 0)
    GBODY(k0 + 32, 1)
  }

  const int nbase = n0 + wn * 64 + L16;
  const int chunk = (n0 >> 6) + wn;
  const int type = chunk % 3;        // 0=q, 1=k, 2=v
  if (type == 2) {
#pragma unroll
    for (int mt = 0; mt < 4; ++mt) {
      const int mbase = m0 + wm * 64 + mt * 16 + quad * 4;
#pragma unroll
      for (int reg = 0; reg < 4; ++reg) {
        const size_t r = (size_t)(mbase + reg) * QKV_N + nbase;
        const unsigned u0 = pk2(acc[mt][0][reg], acc[mt][1][reg]);
        const unsigned u1 = pk2(acc[mt][2][reg], acc[mt][3][reg]);
        qkvb[r]      = (unsigned short)u0;
        qkvb[r + 16] = (unsigned short)(u0 >> 16);
        qkvb[r + 32] = (unsigned short)u1;
        qkvb[r + 48] = (unsigned short)(u1 >> 16);
      }
    }
  } else {
    // q gets 0.125*log2(e) so attention can use bare v_exp (exp2-space).
    const float qs = (type == 0) ? 0.18033688011112042f : 1.0f;
    const float theta = exp2f(-(float)L16 * 0.8304820237218405f);
#pragma unroll
    for (int mt = 0; mt < 4; ++mt) {
      const int mbase = m0 + wm * 64 + mt * 16 + quad * 4;  // even
      const int lb = mbase >> 1;
      float sv[2], cv[2];
      __sincosf((float)lb * theta, &sv[0], &cv[0]);
      __sincosf((float)(lb + 1) * theta, &sv[1], &cv[1]);
#pragma unroll
      for (int reg = 0; reg < 4; ++reg) {
        const int li = reg >> 1;
        const float v0 = acc[mt][0][reg], v1 = acc[mt][1][reg];
        const float r0 = v0 * cv[li] - v1 * sv[li];
        const float r1 = v1 * cv[li] + v0 * sv[li];
        const size_t r = (size_t)(mbase + reg) * QKV_N + nbase;
        const unsigned u0 = pk2(r0 * qs, r1 * qs);
        const unsigned u1 = pk2(acc[mt][2][reg] * qs, acc[mt][3][reg] * qs);
        qkvb[r]      = (unsigned short)u0;
        qkvb[r + 16] = (unsigned short)(u0 >> 16);
        qkvb[r + 32] = (unsigned short)u1;
        qkvb[r + 48] = (unsigned short)(u1 >> 16);
      }
    }
  }
}

// ---------------------------------------------------------------------------
// bf16 MFMA attention -- R7: best-of composition.
//   Base = R2 structure (no KV-split: kt=0..32, grid 16x32, normalized
//   epilogue; R5/R6 showed split's attn gain < merge+traffic cost).
//   Kept from R6: merged QK->exp->PV per-nt inner loop (sc/pf liveness cut,
//   exp on trans pipe interleaves with MFMA; R5->R6 attn -3us) + setprio.
//   launch_bounds(256,2): matches real 2-blocks/CU residency; full 256-reg
//   budget -> no spill risk, max ILP. Occupancy-counter chase abandoned
//   (R6 falsified the register-cap theory; timing is ground truth).
// XOR-swizzled Ks + column-group-swizzled Vt (verified). EXP2 = bare v_exp.
// ---------------------------------------------------------------------------
__global__ __launch_bounds__(256, 2) void attn_mfma_kernel(
    const unsigned short* __restrict__ qkvb, float* __restrict__ out) {
  __shared__ __align__(16) unsigned short Ks[2][4096];    // [buf][r*64 + swz]
  __shared__ __align__(16) unsigned short Vt[2][64][72];  // [buf][d][j] swizzled

  const int t = threadIdx.x;
  const int w = t >> 6;
  const int lane = t & 63;
  const int L16 = lane & 15;
  const int quad = lane >> 4;
  const int l0 = blockIdx.x * 128;
  const int b = blockIdx.y & 1;
  const int h = blockIdx.y >> 1;
  const int hoff = h * HEAD_STRIDE;

  const f32x4 z4 = {0.f, 0.f, 0.f, 0.f};

  // ---- hoisted Q B-fragments for 2 m-tiles ----
  short8_t bq[2][2];
#pragma unroll
  for (int mt = 0; mt < 2; ++mt)
#pragma unroll
    for (int kc = 0; kc < 2; ++kc)
      bq[mt][kc] = *(const short8_t*)
          &qkvb[((size_t)((l0 + w * 32 + mt * 16 + L16) * 2 + b)) * QKV_N +
                hoff + kc * 32 + quad * 8];

  f32x4 oc[2][4];
  float l_part[2] = {0.f, 0.f};
#pragma unroll
  for (int mt = 0; mt < 2; ++mt)
#pragma unroll
    for (int dt = 0; dt < 4; ++dt) oc[mt][dt] = z4;

  // ---- K async-copy state (XOR-swizzled source column) ----
  const int kr0 = w * 8 + (lane >> 3);
  const int kcs = ((lane & 7) ^ (lane >> 3)) * 8;
  const unsigned short* gK0 =
      qkvb + (size_t)(kr0 * 2 + b) * QKV_N + hoff + 64 + kcs;
  const unsigned short* gK1 = gK0 + (size_t)64 * QKV_N;
  const size_t kstep = (size_t)128 * QKV_N;

  // ---- V prefetch state ----
  const int vr4 = (t >> 4) * 4;
  const int vc4 = (t & 15) * 4;
  const int cgbase = vr4 >> 3;
  const int joff = vr4 & 7;
  short4_t rv[4];

#define LOAD_V(KT)                                                            \
  {                                                                           \
    const int j0 = (KT) * 64;                                                 \
    _Pragma("unroll") for (int r = 0; r < 4; ++r)                             \
        rv[r] = *(const short4_t*)&qkvb[((size_t)((j0 + vr4 + r) * 2 + b)) *  \
                                        QKV_N + hoff + 128 + vc4];            \
  }

  LOAD_V(0)
  async_copy16(gK0, &Ks[0][w * 512]);
  async_copy16(gK1, &Ks[0][w * 512 + 2048]);

  const int rsw = (L16 & 7);

#define ABODY(KT, BUF)                                                        \
  {                                                                           \
    { /* V micro-transpose -> Vt[BUF] */                                      \
      short4_t s0 = {rv[0][0], rv[1][0], rv[2][0], rv[3][0]};                 \
      short4_t s1 = {rv[0][1], rv[1][1], rv[2][1], rv[3][1]};                 \
      short4_t s2 = {rv[0][2], rv[1][2], rv[2][2], rv[3][2]};                 \
      short4_t s3 = {rv[0][3], rv[1][3], rv[2][3], rv[3][3]};                 \
      const int cg0 = (cgbase + ((vc4 >> 2) & 7)) & 7;                        \
      *(short4_t*)&Vt[BUF][vc4 + 0][cg0 * 8 + joff] = s0;                     \
      *(short4_t*)&Vt[BUF][vc4 + 1][cg0 * 8 + joff] = s1;                     \
      *(short4_t*)&Vt[BUF][vc4 + 2][cg0 * 8 + joff] = s2;                     \
      *(short4_t*)&Vt[BUF][vc4 + 3][cg0 * 8 + joff] = s3;                     \
    }                                                                         \
    __syncthreads();                                                          \
    if ((KT) + 1 < 32) {                                                      \
      async_copy16(gK0 + (size_t)((KT) + 1) * kstep, &Ks[(BUF) ^ 1][w * 512]);\
      async_copy16(gK1 + (size_t)((KT) + 1) * kstep,                          \
                   &Ks[(BUF) ^ 1][w * 512 + 2048]);                           \
      LOAD_V((KT) + 1)                                                        \
    }                                                                         \
    __builtin_amdgcn_s_setprio(1);                                            \
    _Pragma("unroll") for (int nt = 0; nt < 4; ++nt) {                        \
      const short8_t ak0 = *(const short8_t*)                                 \
          &Ks[BUF][(nt * 16 + L16) * 64 + (quad ^ rsw) * 8];                  \
      const short8_t ak1 = *(const short8_t*)                                 \
          &Ks[BUF][(nt * 16 + L16) * 64 + ((quad + 4) ^ rsw) * 8];            \
      f32x4 t0 = MFMA32(ak0, bq[0][0], z4);                                   \
      const f32x4 s0v = MFMA32(ak1, bq[0][1], t0);                            \
      f32x4 t1 = MFMA32(ak0, bq[1][0], z4);                                   \
      const f32x4 s1v = MFMA32(ak1, bq[1][1], t1);                            \
      float p0 = EXP2(s0v[0]), p1 = EXP2(s0v[1]);                             \
      float p2 = EXP2(s0v[2]), p3 = EXP2(s0v[3]);                             \
      l_part[0] += (p0 + p1) + (p2 + p3);                                     \
      union { short4_t s4; unsigned u[2]; } pu0;                              \
      pu0.u[0] = pk2(p0, p1);                                                 \
      pu0.u[1] = pk2(p2, p3);                                                 \
      float q0 = EXP2(s1v[0]), q1 = EXP2(s1v[1]);                             \
      float q2 = EXP2(s1v[2]), q3 = EXP2(s1v[3]);                             \
      l_part[1] += (q0 + q1) + (q2 + q3);                                     \
      union { short4_t s4; unsigned u[2]; } pu1;                              \
      pu1.u[0] = pk2(q0, q1);                                                 \
      pu1.u[1] = pk2(q2, q3);                                                 \
      _Pragma("unroll") for (int dt = 0; dt < 4; ++dt) {                      \
        const int d = dt * 16 + L16;                                          \
        const int g = 2 * nt + (quad >> 1);                                   \
        const int cg = (g + ((d >> 2) & 7)) & 7;                              \
        const short4_t vf =                                                   \
            *(const short4_t*)&Vt[BUF][d][cg * 8 + (quad & 1) * 4];           \
        oc[0][dt] = MFMA16(vf, pu0.s4, oc[0][dt]);                            \
        oc[1][dt] = MFMA16(vf, pu1.s4, oc[1][dt]);                            \
      }                                                                       \
    }                                                                         \
    __builtin_amdgcn_s_setprio(0);                                            \
  }

  for (int kt = 0; kt < 32; kt += 2) {
    ABODY(kt, 0)
    ABODY(kt + 1, 1)
  }

  // ---- final row-sum reductions + epilogue ----
#pragma unroll
  for (int mt = 0; mt < 2; ++mt) {
    float l = l_part[mt];
    l += __shfl_xor(l, 16);
    l += __shfl_xor(l, 32);
    const float inv = 1.f / l;
    const int qrow = l0 + w * 32 + mt * 16 + L16;
    const size_t rbase = ((size_t)(qrow * 2 + b)) * DM + h * DK;
#pragma unroll
    for (int dt = 0; dt < 4; ++dt) {
      *(float4*)&out[rbase + dt * 16 + quad * 4] =
          make_float4(oc[mt][dt][0] * inv, oc[mt][dt][1] * inv,
                      oc[mt][dt][2] * inv, oc[mt][dt][3] * inv);
    }
  }
}

// ---------------------------------------------------------------------------
extern "C" void kernel_launch(void* const* d_in, const int* in_sizes, int n_in,
                              void* d_out, int out_size, void* d_ws,
                              size_t ws_size, hipStream_t stream) {
  const float* x = (const float*)d_in[0];
  const float* w = (const float*)d_in[1];
  float* out = (float*)d_out;
  unsigned short* bf = (unsigned short*)d_ws;          // Xb (8MB) + Wb (6MB)
  unsigned short* Xb = bf;
  unsigned short* Wb = bf + NX;
  unsigned short* qkvb =
      (unsigned short*)((char*)d_ws + (16u << 20));    // 24 MB bf16 qkv

  cast_kernel<<<(NX + NW) / (256 * 8), 256, 0, stream>>>(x, w, bf);
  qkv_gemm_bf16<<<dim3(QKV_N / 128, (L_SEQ * BATCH) / 128), 256, 0, stream>>>(
      Xb, Wb, qkvb);
  attn_mfma_kernel<<<dim3(L_SEQ / 128, NH * BATCH), 256, 0, stream>>>(qkvb, out);
}

// Round 8
// 160.661 us; speedup vs baseline: 1.3521x; 1.0235x over previous
//
#include <hip/hip_runtime.h>
#include <hip/hip_bf16.h>
#include <cstdint>
#include <cstddef>

#define L_SEQ 2048
#define BATCH 2
#define DM 1024
#define NH 16
#define DK 64
#define QKV_N 3072       // 3*DM (logical GEMM output width)
#define QK_N 2048        // packed q|k buffer width (V lives in vtb)
#define NX (4096 * 1024) // X element count
#define NW (3072 * 1024) // W element count

typedef short short8_t __attribute__((ext_vector_type(8)));
typedef short short4_t __attribute__((ext_vector_type(4)));
typedef float f32x4 __attribute__((ext_vector_type(4)));

#define MFMA32(a, b, c) __builtin_amdgcn_mfma_f32_16x16x32_bf16(a, b, c, 0, 0, 0)
#define MFMA16(a, b, c) __builtin_amdgcn_mfma_f32_16x16x16bf16_1k(a, b, c, 0, 0, 0)
// bare v_exp_f32 (2^x). exp2f() is an OCML libm call -- R10 regression.
#define EXP2(x) __builtin_amdgcn_exp2f(x)

// 2x fp32 -> packed bf16 pair (v_cvt_pk_bf16_f32 on gfx950), RNE.
static __device__ __forceinline__ unsigned pk2(float a, float b) {
  __hip_bfloat162 h = __float22bfloat162_rn(make_float2(a, b));
  union { __hip_bfloat162 h; unsigned u; } v;
  v.h = h;
  return v.u;
}

// async global->LDS, 16B per lane. LDS dest = wave-uniform base + lane*16.
static __device__ __forceinline__ void async_copy16(const unsigned short* g,
                                                    unsigned short* l) {
  __builtin_amdgcn_global_load_lds(
      (const __attribute__((address_space(1))) unsigned int*)g,
      (__attribute__((address_space(3))) unsigned int*)l, 16, 0, 0);
}

// ---------------------------------------------------------------------------
// fp32 -> bf16 cast of X and W into one contiguous bf16 buffer.
// ---------------------------------------------------------------------------
__global__ __launch_bounds__(256) void cast_kernel(
    const float* __restrict__ X, const float* __restrict__ W,
    unsigned short* __restrict__ dst) {
  const int e = (blockIdx.x * 256 + threadIdx.x) * 8;
  const float* src = (e < NX) ? &X[e] : &W[e - NX];
  const float4 v0 = *(const float4*)src;
  const float4 v1 = *(const float4*)(src + 4);
  union { short8_t s8; unsigned u[4]; } o;
  o.u[0] = pk2(v0.x, v0.y);
  o.u[1] = pk2(v0.z, v0.w);
  o.u[2] = pk2(v1.x, v1.y);
  o.u[3] = pk2(v1.z, v1.w);
  *(short8_t*)&dst[e] = o.s8;
}

// ---------------------------------------------------------------------------
// bf16 MFMA QKV GEMM, fused RoPE + q-scale epilogue, bf16 output.
// R8: output split into two buffers.
//   qkb [4096][2048]: interleaved rows (l*2+b), cols h*128 + {q:0|k:64} + d.
//   vtb [b][h][64 d][2048 j]: V stored TRANSPOSED (j = seq pos). The GEMM
//   epilogue was already a scalar scatter; writing V^T here costs the same
//   (j-pairs pack to u32, 4 quads -> 16B contiguous) and deletes the entire
//   per-step V register-transpose in attention.
// q-scale = 0.125 * log2(e): attention computes softmax in exp2-space.
// NOTE: no setprio here -- m190 measured T5 null/negative on lockstep GEMM.
// ---------------------------------------------------------------------------
__global__ __launch_bounds__(256) void qkv_gemm_bf16(
    const unsigned short* __restrict__ Xb, const unsigned short* __restrict__ Wb,
    unsigned short* __restrict__ qkb, unsigned short* __restrict__ vtb) {
  __shared__ __align__(16) unsigned short As[2][128 * 32];  // [buf][m][k]
  __shared__ __align__(16) unsigned short Bs[2][128 * 32];  // [buf][n][k]
  const int t = threadIdx.x;
  const int w = t >> 6;
  const int lane = t & 63;
  const int L16 = lane & 15;
  const int quad = lane >> 4;
  const int m0 = blockIdx.y * 128;
  const int n0 = blockIdx.x * 128;
  const int wm = w & 1;
  const int wn = w >> 1;

  const int c0 = w * 128 + lane;
  const int c1 = c0 + 64;
  const unsigned short* gA0 = Xb + (size_t)(m0 + (c0 >> 2)) * 1024 + (c0 & 3) * 8;
  const unsigned short* gA1 = Xb + (size_t)(m0 + (c1 >> 2)) * 1024 + (c1 & 3) * 8;
  const unsigned short* gB0 = Wb + (size_t)(n0 + (c0 >> 2)) * 1024 + (c0 & 3) * 8;
  const unsigned short* gB1 = Wb + (size_t)(n0 + (c1 >> 2)) * 1024 + (c1 & 3) * 8;

  f32x4 acc[4][4];
#pragma unroll
  for (int i = 0; i < 4; ++i)
#pragma unroll
    for (int j = 0; j < 4; ++j) acc[i][j] = (f32x4){0.f, 0.f, 0.f, 0.f};

  // prologue: stage tile 0 into buf 0
  async_copy16(gA0, &As[0][w * 1024]);
  async_copy16(gA1, &As[0][w * 1024 + 512]);
  async_copy16(gB0, &Bs[0][w * 1024]);
  async_copy16(gB1, &Bs[0][w * 1024 + 512]);

#define GBODY(K0, BUF)                                                        \
  {                                                                           \
    __syncthreads(); /* drains DMA(K0); prior readers of buf done */          \
    if ((K0) + 32 < 1024) {                                                   \
      async_copy16(gA0 + (K0) + 32, &As[(BUF) ^ 1][w * 1024]);                \
      async_copy16(gA1 + (K0) + 32, &As[(BUF) ^ 1][w * 1024 + 512]);          \
      async_copy16(gB0 + (K0) + 32, &Bs[(BUF) ^ 1][w * 1024]);                \
      async_copy16(gB1 + (K0) + 32, &Bs[(BUF) ^ 1][w * 1024 + 512]);          \
    }                                                                         \
    short8_t af[4], bfr[4];                                                   \
    _Pragma("unroll") for (int mt = 0; mt < 4; ++mt)                          \
        af[mt] = *(const short8_t*)                                           \
            &As[BUF][(wm * 64 + mt * 16 + L16) * 32 + quad * 8];              \
    _Pragma("unroll") for (int nt = 0; nt < 4; ++nt)                          \
        bfr[nt] = *(const short8_t*)                                          \
            &Bs[BUF][(wn * 64 + nt * 16 + L16) * 32 + quad * 8];              \
    _Pragma("unroll") for (int mt = 0; mt < 4; ++mt)                          \
        _Pragma("unroll") for (int nt = 0; nt < 4; ++nt)                      \
            acc[mt][nt] = MFMA32(af[mt], bfr[nt], acc[mt][nt]);               \
  }

  for (int k0 = 0; k0 < 1024; k0 += 64) {
    GBODY(k0, 0)
    GBODY(k0 + 32, 1)
  }

  const int chunk = (n0 >> 6) + wn;  // 64-col chunk in logical qkv order
  const int h = chunk / 3;
  const int type = chunk % 3;        // 0=q, 1=k, 2=v
  if (type == 2) {
    // V^T store: vtb[((b*16+h)*64 + d)*2048 + j].
    // reg 0,2 -> b=0 (j=lb,lb+1); reg 1,3 -> b=1. u32 packs the j-pair.
#pragma unroll
    for (int mt = 0; mt < 4; ++mt) {
      const int mbase = m0 + wm * 64 + mt * 16 + quad * 4;  // even
      const int lb = mbase >> 1;
#pragma unroll
      for (int nt = 0; nt < 4; ++nt) {
        const int d = L16 + nt * 16;
        const size_t r0 = ((size_t)(h * 64 + d)) * 2048 + lb;           // b=0
        const size_t r1 = ((size_t)((16 + h) * 64 + d)) * 2048 + lb;    // b=1
        *(unsigned*)&vtb[r0] = pk2(acc[mt][nt][0], acc[mt][nt][2]);
        *(unsigned*)&vtb[r1] = pk2(acc[mt][nt][1], acc[mt][nt][3]);
      }
    }
  } else {
    // q gets 0.125*log2(e) so attention can use bare v_exp (exp2-space).
    const float qs = (type == 0) ? 0.18033688011112042f : 1.0f;
    const int cbase = h * 128 + type * 64 + L16;
    const float theta = exp2f(-(float)L16 * 0.8304820237218405f);
#pragma unroll
    for (int mt = 0; mt < 4; ++mt) {
      const int mbase = m0 + wm * 64 + mt * 16 + quad * 4;  // even
      const int lb = mbase >> 1;
      float sv[2], cv[2];
      __sincosf((float)lb * theta, &sv[0], &cv[0]);
      __sincosf((float)(lb + 1) * theta, &sv[1], &cv[1]);
#pragma unroll
      for (int reg = 0; reg < 4; ++reg) {
        const int li = reg >> 1;
        const float v0 = acc[mt][0][reg], v1 = acc[mt][1][reg];
        const float r0 = v0 * cv[li] - v1 * sv[li];
        const float r1 = v1 * cv[li] + v0 * sv[li];
        const size_t r = (size_t)(mbase + reg) * QK_N + cbase;
        const unsigned u0 = pk2(r0 * qs, r1 * qs);
        const unsigned u1 = pk2(acc[mt][2][reg] * qs, acc[mt][3][reg] * qs);
        qkb[r]      = (unsigned short)u0;
        qkb[r + 16] = (unsigned short)(u0 >> 16);
        qkb[r + 32] = (unsigned short)u1;
        qkb[r + 48] = (unsigned short)(u1 >> 16);
      }
    }
  }
}

// ---------------------------------------------------------------------------
// bf16 MFMA attention -- R8: V staged by DMA like K (register-transpose gone).
//   R7 counters: VALUBusy 40% > MfmaUtil 34%; per-step pre-barrier path held
//   4 per-lane V loads + ~12 transpose VALU + 4 ds_write_b64 + their bank
//   conflicts. V now arrives pre-transposed from the GEMM (vtb), staged with
//   2 async_copy16/wave using the XOR-source idiom (rule #21: linear LDS
//   dest + inverse-swizzled SOURCE + XOR on READ -- same involution as the
//   verified K path). PV read: Vs[d][j ^ ((d&7)<<3)], conflict-free
//   (8 banks x 2-way within 16-lane group; 2-way is free, m136).
// Kept from R7: merged QK->exp->PV per-nt loop, setprio, lb(256,2).
// ---------------------------------------------------------------------------
__global__ __launch_bounds__(256, 2) void attn_mfma_kernel(
    const unsigned short* __restrict__ qkb,
    const unsigned short* __restrict__ vtb, float* __restrict__ out) {
  __shared__ __align__(16) unsigned short Ks[2][4096];  // [buf][j*64 + swz(k)]
  __shared__ __align__(16) unsigned short Vs[2][4096];  // [buf][d*64 + swz(j)]

  const int t = threadIdx.x;
  const int w = t >> 6;
  const int lane = t & 63;
  const int L16 = lane & 15;
  const int quad = lane >> 4;
  const int l0 = blockIdx.x * 128;
  const int b = blockIdx.y & 1;
  const int h = blockIdx.y >> 1;
  const int vh = b * 16 + h;

  const f32x4 z4 = {0.f, 0.f, 0.f, 0.f};

  // ---- hoisted Q B-fragments for 2 m-tiles ----
  short8_t bq[2][2];
#pragma unroll
  for (int mt = 0; mt < 2; ++mt)
#pragma unroll
    for (int kc = 0; kc < 2; ++kc)
      bq[mt][kc] = *(const short8_t*)
          &qkb[((size_t)((l0 + w * 32 + mt * 16 + L16) * 2 + b)) * QK_N +
               h * 128 + kc * 32 + quad * 8];

  f32x4 oc[2][4];
  float l_part[2] = {0.f, 0.f};
#pragma unroll
  for (int mt = 0; mt < 2; ++mt)
#pragma unroll
    for (int dt = 0; dt < 4; ++dt) oc[mt][dt] = z4;

  // ---- K async-copy state (XOR-swizzled source column) ----
  const int kr0 = w * 8 + (lane >> 3);
  const int kcs = ((lane & 7) ^ (lane >> 3)) * 8;
  const unsigned short* gK0 =
      qkb + (size_t)(kr0 * 2 + b) * QK_N + h * 128 + 64 + kcs;
  const unsigned short* gK1 = gK0 + (size_t)64 * QK_N;
  const size_t kstep = (size_t)128 * QK_N;

  // ---- V async-copy state: lane covers d = w*8 + (lane>>3) (+32 for gV1),
  //      source j-group inverse-swizzled so LDS image = V^T[d][j ^ swz(d)].
  const unsigned short* gV0 =
      vtb + ((size_t)(vh * 64 + w * 8 + (lane >> 3))) * 2048 +
      (((lane & 7) ^ (lane >> 3)) << 3);
  const unsigned short* gV1 = gV0 + (size_t)32 * 2048;

  // prologue: stage tile 0 into buf 0
  async_copy16(gK0, &Ks[0][w * 512]);
  async_copy16(gK1, &Ks[0][w * 512 + 2048]);
  async_copy16(gV0, &Vs[0][w * 512]);
  async_copy16(gV1, &Vs[0][w * 512 + 2048]);

  const int rsw = (L16 & 7);
  const int vswz = (L16 & 7) << 3;

#define ABODY(KT, BUF)                                                        \
  {                                                                           \
    __syncthreads(); /* drains DMA(BUF); prior readers of BUF^1 done */       \
    if ((KT) + 1 < 32) {                                                      \
      async_copy16(gK0 + (size_t)((KT) + 1) * kstep, &Ks[(BUF) ^ 1][w * 512]);\
      async_copy16(gK1 + (size_t)((KT) + 1) * kstep,                          \
                   &Ks[(BUF) ^ 1][w * 512 + 2048]);                           \
      async_copy16(gV0 + ((KT) + 1) * 64, &Vs[(BUF) ^ 1][w * 512]);           \
      async_copy16(gV1 + ((KT) + 1) * 64, &Vs[(BUF) ^ 1][w * 512 + 2048]);    \
    }                                                                         \
    __builtin_amdgcn_s_setprio(1);                                            \
    _Pragma("unroll") for (int nt = 0; nt < 4; ++nt) {                        \
      const short8_t ak0 = *(const short8_t*)                                 \
          &Ks[BUF][(nt * 16 + L16) * 64 + (quad ^ rsw) * 8];                  \
      const short8_t ak1 = *(const short8_t*)                                 \
          &Ks[BUF][(nt * 16 + L16) * 64 + ((quad + 4) ^ rsw) * 8];            \
      f32x4 t0 = MFMA32(ak0, bq[0][0], z4);                                   \
      const f32x4 s0v = MFMA32(ak1, bq[0][1], t0);                            \
      f32x4 t1 = MFMA32(ak0, bq[1][0], z4);                                   \
      const f32x4 s1v = MFMA32(ak1, bq[1][1], t1);                            \
      float p0 = EXP2(s0v[0]), p1 = EXP2(s0v[1]);                             \
      float p2 = EXP2(s0v[2]), p3 = EXP2(s0v[3]);                             \
      l_part[0] += (p0 + p1) + (p2 + p3);                                     \
      union { short4_t s4; unsigned u[2]; } pu0;                              \
      pu0.u[0] = pk2(p0, p1);                                                 \
      pu0.u[1] = pk2(p2, p3);                                                 \
      float q0 = EXP2(s1v[0]), q1 = EXP2(s1v[1]);                             \
      float q2 = EXP2(s1v[2]), q3 = EXP2(s1v[3]);                             \
      l_part[1] += (q0 + q1) + (q2 + q3);                                     \
      union { short4_t s4; unsigned u[2]; } pu1;                              \
      pu1.u[0] = pk2(q0, q1);                                                 \
      pu1.u[1] = pk2(q2, q3);                                                 \
      _Pragma("unroll") for (int dt = 0; dt < 4; ++dt) {                      \
        const short4_t vf = *(const short4_t*)                                \
            &Vs[BUF][(dt * 16 + L16) * 64 + ((nt * 16 + quad * 4) ^ vswz)];   \
        oc[0][dt] = MFMA16(vf, pu0.s4, oc[0][dt]);                            \
        oc[1][dt] = MFMA16(vf, pu1.s4, oc[1][dt]);                            \
      }                                                                       \
    }                                                                         \
    __builtin_amdgcn_s_setprio(0);                                            \
  }

  for (int kt = 0; kt < 32; kt += 2) {
    ABODY(kt, 0)
    ABODY(kt + 1, 1)
  }

  // ---- final row-sum reductions + epilogue ----
#pragma unroll
  for (int mt = 0; mt < 2; ++mt) {
    float l = l_part[mt];
    l += __shfl_xor(l, 16);
    l += __shfl_xor(l, 32);
    const float inv = 1.f / l;
    const int qrow = l0 + w * 32 + mt * 16 + L16;
    const size_t rbase = ((size_t)(qrow * 2 + b)) * DM + h * DK;
#pragma unroll
    for (int dt = 0; dt < 4; ++dt) {
      *(float4*)&out[rbase + dt * 16 + quad * 4] =
          make_float4(oc[mt][dt][0] * inv, oc[mt][dt][1] * inv,
                      oc[mt][dt][2] * inv, oc[mt][dt][3] * inv);
    }
  }
}

// ---------------------------------------------------------------------------
extern "C" void kernel_launch(void* const* d_in, const int* in_sizes, int n_in,
                              void* d_out, int out_size, void* d_ws,
                              size_t ws_size, hipStream_t stream) {
  const float* x = (const float*)d_in[0];
  const float* w = (const float*)d_in[1];
  float* out = (float*)d_out;
  unsigned short* bf = (unsigned short*)d_ws;          // Xb (8MB) + Wb (6MB)
  unsigned short* Xb = bf;
  unsigned short* Wb = bf + NX;
  unsigned short* qkb =
      (unsigned short*)((char*)d_ws + (16u << 20));    // 16 MB bf16 q|k
  unsigned short* vtb =
      (unsigned short*)((char*)d_ws + (32u << 20));    // 8 MB bf16 V^T

  cast_kernel<<<(NX + NW) / (256 * 8), 256, 0, stream>>>(x, w, bf);
  qkv_gemm_bf16<<<dim3(QKV_N / 128, (L_SEQ * BATCH) / 128), 256, 0, stream>>>(
      Xb, Wb, qkb, vtb);
  attn_mfma_kernel<<<dim3(L_SEQ / 128, NH * BATCH), 256, 0, stream>>>(qkb, vtb,
                                                                      out);
}